// Round 12
// baseline (745.225 us; speedup 1.0000x reference)
//
#include <hip/hip_runtime.h>
#include <math.h>

#define B_    32
#define NB_   1024
#define H_    768
#define K_    384
#define C_    64
#define MC_   128                // rows per gate block
#define NSTEP_ 24                // K-steps of 32

typedef __attribute__((ext_vector_type(8))) short bf16x8;
typedef __attribute__((ext_vector_type(4))) float f32x4;

__device__ __forceinline__ short f2bf(float f) {   // RNE fp32 -> bf16 bits
    unsigned u = __float_as_uint(f);
    unsigned r = (u + 0x7fffu + ((u >> 16) & 1u)) >> 16;
    return (short)r;
}
__device__ __forceinline__ bf16x8 cvt8(const float4& a, const float4& b) {
    bf16x8 v = { f2bf(a.x), f2bf(a.y), f2bf(a.z), f2bf(a.w),
                 f2bf(b.x), f2bf(b.y), f2bf(b.z), f2bf(b.w) };
    return v;
}
__device__ __forceinline__ float ftanh(float x) {  // tanh = 1 - 2/(e^2x+1)
    float e = __expf(2.f * x);
    return 1.f - 2.f * __builtin_amdgcn_rcpf(e + 1.f);
}
__device__ __forceinline__ void gload_lds16(const void* g, void* l) {
    __builtin_amdgcn_global_load_lds(
        (const __attribute__((address_space(1))) unsigned int*)g,
        (__attribute__((address_space(3))) unsigned int*)l, 16, 0, 0);
}

// ---------------------------------------------------------------------------
// W1 -> bf16, fragment-ordered per (nt, step): 8KB contiguous slabs.
// ---------------------------------------------------------------------------
__global__ __launch_bounds__(256) void prep_w1(const float* __restrict__ W1,
                                               short* __restrict__ swz)
{
    int idx = blockIdx.x * 256 + threadIdx.x;
    int k = idx / K_, n = idx % K_;
    float v = W1[idx];
    int step = k >> 5, lg = (k >> 3) & 3, i = k & 7;
    int nt = n >> 7, cf = (n >> 4) & 7, nn = n & 15;
    swz[(((nt * 24 + step) * 8) + cf) * 512 + (lg * 16 + nn) * 8 + i] = f2bf(v);
}

// ---------------------------------------------------------------------------
__global__ __launch_bounds__(1024) void compact_kernel(
    const int* __restrict__ active, int* __restrict__ list, int* __restrict__ cnt)
{
    __shared__ int wsum[16];
    __shared__ int wbase[17];
    const int b = blockIdx.x, tid = threadIdx.x, lane = tid & 63, wid = tid >> 6;
    const int flag = active[b * NB_ + tid] != 0;
    const unsigned long long m = __ballot(flag);
    if (lane == 0) wsum[wid] = __popcll(m);
    __syncthreads();
    if (tid == 0) {
        int r = 0;
        for (int i = 0; i < 16; ++i) { wbase[i] = r; r += wsum[i]; }
        wbase[16] = r;
        cnt[b] = r;
    }
    __syncthreads();
    const int total = wbase[16];
    if (flag) {
        const int pos = wbase[wid] + __popcll(m & ((1ull << lane) - 1ull));
        list[b * NB_ + pos] = tid;
    }
    if (tid >= total) list[b * NB_ + tid] = 0;
}

// ---------------------------------------------------------------------------
// Gate (r11, unchanged, passing): 128x128xK768, m97-style staging.
// ---------------------------------------------------------------------------
__global__ __launch_bounds__(256, 3) void gate_kernel(
    const float* __restrict__ tokens, const short* __restrict__ swz,
    const float* __restrict__ b1, const float* __restrict__ W2,
    const int* __restrict__ list, const int* __restrict__ cnt,
    float* __restrict__ gate_part)
{
    __shared__ __align__(16) short As[2][4096];
    __shared__ __align__(16) short Bs[2][4096];

    const int bx   = blockIdx.x;
    const int b    = bx / 24;
    const int rem  = bx - b * 24;
    const int chunk = rem / 3;
    const int nt   = rem - chunk * 3;
    if (chunk * MC_ >= cnt[b]) return;

    const int tid  = threadIdx.x;
    const int lane = tid & 63;
    const int w    = tid >> 6;
    const int lrow = lane & 15;
    const int kg   = lane >> 4;

    const int r = tid >> 1, h = tid & 1;
    const int nrow = list[b * NB_ + chunk * MC_ + r];
    const float* aptr = tokens + ((size_t)b * NB_ + nrow) * H_ + h * 16;
    const int rg = r >> 4, arow = r & 15;
    const int woffA0 = ((rg * 4 + 2 * h)     * 16 + (arow ^ (4 * h)))     * 8;
    const int woffA1 = ((rg * 4 + 2 * h + 1) * 16 + (arow ^ (4 * h + 2))) * 8;

    const char* bsrc = (const char*)swz + (size_t)nt * 196608 + w * 1024 + lane * 16;
    char* bdst0 = (char*)&Bs[0][0] + w * 1024;
    char* bdst1 = (char*)&Bs[1][0] + w * 1024;

    const int roff0 = (((2 * w + 0) * 4 + kg) * 16 + (lrow ^ (kg << 1))) * 8;
    const int roff1 = (((2 * w + 1) * 4 + kg) * 16 + (lrow ^ (kg << 1))) * 8;

    f32x4 acc[8][2];
#pragma unroll
    for (int cf = 0; cf < 8; ++cf)
#pragma unroll
        for (int q = 0; q < 2; ++q) acc[cf][q] = (f32x4){0.f, 0.f, 0.f, 0.f};

    float4 pe0, pe1, pe2, pe3, po0, po1, po2, po3;

    gload_lds16(bsrc,        bdst0);
    gload_lds16(bsrc + 4096, bdst0 + 4096);
    pe0 = *(const float4*)(aptr);
    pe1 = *(const float4*)(aptr + 4);
    pe2 = *(const float4*)(aptr + 8);
    pe3 = *(const float4*)(aptr + 12);
    po0 = *(const float4*)(aptr + 32);
    po1 = *(const float4*)(aptr + 36);
    po2 = *(const float4*)(aptr + 40);
    po3 = *(const float4*)(aptr + 44);
    *(bf16x8*)&As[0][woffA0] = cvt8(pe0, pe1);
    *(bf16x8*)&As[0][woffA1] = cvt8(pe2, pe3);
    __syncthreads();

    for (int s = 0; s < NSTEP_; s += 2) {
        {
            const char* bp = bsrc + (size_t)(s + 1) * 8192;
            gload_lds16(bp,        bdst1);
            gload_lds16(bp + 4096, bdst1 + 4096);
        }
        if (s + 2 < NSTEP_) {
            pe0 = *(const float4*)(aptr + (s + 2) * 32);
            pe1 = *(const float4*)(aptr + (s + 2) * 32 + 4);
            pe2 = *(const float4*)(aptr + (s + 2) * 32 + 8);
            pe3 = *(const float4*)(aptr + (s + 2) * 32 + 12);
        }
        *(bf16x8*)&As[1][woffA0] = cvt8(po0, po1);
        *(bf16x8*)&As[1][woffA1] = cvt8(po2, po3);
        {
            bf16x8 a0 = *(const bf16x8*)&As[0][roff0];
            bf16x8 a1 = *(const bf16x8*)&As[0][roff1];
#pragma unroll
            for (int cf = 0; cf < 8; ++cf) {
                bf16x8 bv = *(const bf16x8*)&Bs[0][cf * 512 + lane * 8];
                acc[cf][0] = __builtin_amdgcn_mfma_f32_16x16x32_bf16(a0, bv, acc[cf][0], 0, 0, 0);
                acc[cf][1] = __builtin_amdgcn_mfma_f32_16x16x32_bf16(a1, bv, acc[cf][1], 0, 0, 0);
            }
        }
        __syncthreads();

        if (s + 2 < NSTEP_) {
            const char* bp = bsrc + (size_t)(s + 2) * 8192;
            gload_lds16(bp,        bdst0);
            gload_lds16(bp + 4096, bdst0 + 4096);
        }
        if (s + 3 < NSTEP_) {
            po0 = *(const float4*)(aptr + (s + 3) * 32);
            po1 = *(const float4*)(aptr + (s + 3) * 32 + 4);
            po2 = *(const float4*)(aptr + (s + 3) * 32 + 8);
            po3 = *(const float4*)(aptr + (s + 3) * 32 + 12);
        }
        if (s + 2 < NSTEP_) {
            *(bf16x8*)&As[0][woffA0] = cvt8(pe0, pe1);
            *(bf16x8*)&As[0][woffA1] = cvt8(pe2, pe3);
        }
        {
            bf16x8 a0 = *(const bf16x8*)&As[1][roff0];
            bf16x8 a1 = *(const bf16x8*)&As[1][roff1];
#pragma unroll
            for (int cf = 0; cf < 8; ++cf) {
                bf16x8 bv = *(const bf16x8*)&Bs[1][cf * 512 + lane * 8];
                acc[cf][0] = __builtin_amdgcn_mfma_f32_16x16x32_bf16(a0, bv, acc[cf][0], 0, 0, 0);
                acc[cf][1] = __builtin_amdgcn_mfma_f32_16x16x32_bf16(a1, bv, acc[cf][1], 0, 0, 0);
            }
        }
        __syncthreads();
    }

    float ps[2][4];
#pragma unroll
    for (int q = 0; q < 2; ++q)
#pragma unroll
        for (int i = 0; i < 4; ++i) ps[q][i] = 0.f;

#pragma unroll
    for (int cf = 0; cf < 8; ++cf) {
        const int n = nt * 128 + cf * 16 + lrow;
        const float bb = b1[n];
        const float ww = W2[n];
#pragma unroll
        for (int q = 0; q < 2; ++q)
#pragma unroll
            for (int i = 0; i < 4; ++i)
                ps[q][i] += ftanh(acc[cf][q][i] + bb) * ww;
    }
#pragma unroll
    for (int m = 1; m < 16; m <<= 1)
#pragma unroll
        for (int q = 0; q < 2; ++q)
#pragma unroll
            for (int i = 0; i < 4; ++i)
                ps[q][i] += __shfl_xor(ps[q][i], m, 64);

    if (lrow == 0) {
        float* gp = gate_part + (size_t)nt * (B_ * NB_) + b * NB_;
#pragma unroll
        for (int q = 0; q < 2; ++q)
#pragma unroll
            for (int i = 0; i < 4; ++i) {
                const int rl = w * 32 + q * 16 + kg * 4 + i;
                gp[list[b * NB_ + chunk * MC_ + rl]] = ps[q][i];
            }
    }
}

// ---------------------------------------------------------------------------
// PROBE kernels (diagnostic): MODE bit0 = A-path, bit1 = B-path; MODE 0 =
// MFMA-only (no memory, no barriers). REP repeats of the k-loop. Results go
// to ws scratch (kept live; never read by the harness).
// ---------------------------------------------------------------------------
template<int MODE, int REP>
__global__ __launch_bounds__(256, 3) void probe_kernel(
    const float* __restrict__ tokens, const short* __restrict__ swz,
    const int* __restrict__ list, const int* __restrict__ cnt,
    float* __restrict__ outp)
{
    __shared__ __align__(16) short As[2][4096];
    __shared__ __align__(16) short Bs[2][4096];

    const int bx   = blockIdx.x;
    const int b    = bx / 24;
    const int rem  = bx - b * 24;
    const int chunk = rem / 3;
    const int nt   = rem - chunk * 3;
    if (chunk * MC_ >= cnt[b]) return;

    const int tid  = threadIdx.x;
    const int lane = tid & 63;
    const int w    = tid >> 6;
    const int lrow = lane & 15;
    const int kg   = lane >> 4;

    const int r = tid >> 1, h = tid & 1;
    const int nrow = list[b * NB_ + chunk * MC_ + r];
    const float* aptr = tokens + ((size_t)b * NB_ + nrow) * H_ + h * 16;
    const int rg = r >> 4, arow = r & 15;
    const int woffA0 = ((rg * 4 + 2 * h)     * 16 + (arow ^ (4 * h)))     * 8;
    const int woffA1 = ((rg * 4 + 2 * h + 1) * 16 + (arow ^ (4 * h + 2))) * 8;

    const char* bsrc = (const char*)swz + (size_t)nt * 196608 + w * 1024 + lane * 16;
    char* bdst0 = (char*)&Bs[0][0] + w * 1024;
    char* bdst1 = (char*)&Bs[1][0] + w * 1024;

    const int roff0 = (((2 * w + 0) * 4 + kg) * 16 + (lrow ^ (kg << 1))) * 8;
    const int roff1 = (((2 * w + 1) * 4 + kg) * 16 + (lrow ^ (kg << 1))) * 8;

    f32x4 acc[8][2];
#pragma unroll
    for (int cf = 0; cf < 8; ++cf)
#pragma unroll
        for (int q = 0; q < 2; ++q) acc[cf][q] = (f32x4){0.f, 0.f, 0.f, 0.f};

    bf16x8 ac;           // constant operand for disabled paths
#pragma unroll
    for (int i = 0; i < 8; ++i) ac[i] = (short)(0x3f80 + lane + i);

#pragma unroll 1
    for (int rep = 0; rep < REP; ++rep) {
        if constexpr (MODE == 0) {
#pragma unroll 1
            for (int s = 0; s < NSTEP_; ++s) {
#pragma unroll
                for (int cf = 0; cf < 8; ++cf) {
                    acc[cf][0] = __builtin_amdgcn_mfma_f32_16x16x32_bf16(ac, ac, acc[cf][0], 0, 0, 0);
                    acc[cf][1] = __builtin_amdgcn_mfma_f32_16x16x32_bf16(ac, ac, acc[cf][1], 0, 0, 0);
                }
            }
        } else {
            float4 pe0, pe1, pe2, pe3, po0, po1, po2, po3;
            if constexpr (MODE & 2) {
                gload_lds16(bsrc,        bdst0);
                gload_lds16(bsrc + 4096, bdst0 + 4096);
            }
            if constexpr (MODE & 1) {
                pe0 = *(const float4*)(aptr);
                pe1 = *(const float4*)(aptr + 4);
                pe2 = *(const float4*)(aptr + 8);
                pe3 = *(const float4*)(aptr + 12);
                po0 = *(const float4*)(aptr + 32);
                po1 = *(const float4*)(aptr + 36);
                po2 = *(const float4*)(aptr + 40);
                po3 = *(const float4*)(aptr + 44);
                *(bf16x8*)&As[0][woffA0] = cvt8(pe0, pe1);
                *(bf16x8*)&As[0][woffA1] = cvt8(pe2, pe3);
            }
            __syncthreads();
#pragma unroll 1
            for (int s = 0; s < NSTEP_; s += 2) {
                if constexpr (MODE & 2) {
                    const char* bp = bsrc + (size_t)(s + 1) * 8192;
                    gload_lds16(bp,        bdst1);
                    gload_lds16(bp + 4096, bdst1 + 4096);
                }
                if constexpr (MODE & 1) {
                    if (s + 2 < NSTEP_) {
                        pe0 = *(const float4*)(aptr + (s + 2) * 32);
                        pe1 = *(const float4*)(aptr + (s + 2) * 32 + 4);
                        pe2 = *(const float4*)(aptr + (s + 2) * 32 + 8);
                        pe3 = *(const float4*)(aptr + (s + 2) * 32 + 12);
                    }
                    *(bf16x8*)&As[1][woffA0] = cvt8(po0, po1);
                    *(bf16x8*)&As[1][woffA1] = cvt8(po2, po3);
                }
                {
                    bf16x8 a0 = (MODE & 1) ? *(const bf16x8*)&As[0][roff0] : ac;
                    bf16x8 a1 = (MODE & 1) ? *(const bf16x8*)&As[0][roff1] : ac;
#pragma unroll
                    for (int cf = 0; cf < 8; ++cf) {
                        bf16x8 bv = (MODE & 2) ? *(const bf16x8*)&Bs[0][cf * 512 + lane * 8] : ac;
                        acc[cf][0] = __builtin_amdgcn_mfma_f32_16x16x32_bf16(a0, bv, acc[cf][0], 0, 0, 0);
                        acc[cf][1] = __builtin_amdgcn_mfma_f32_16x16x32_bf16(a1, bv, acc[cf][1], 0, 0, 0);
                    }
                }
                __syncthreads();

                if constexpr (MODE & 2) {
                    if (s + 2 < NSTEP_) {
                        const char* bp = bsrc + (size_t)(s + 2) * 8192;
                        gload_lds16(bp,        bdst0);
                        gload_lds16(bp + 4096, bdst0 + 4096);
                    }
                }
                if constexpr (MODE & 1) {
                    if (s + 3 < NSTEP_) {
                        po0 = *(const float4*)(aptr + (s + 3) * 32);
                        po1 = *(const float4*)(aptr + (s + 3) * 32 + 4);
                        po2 = *(const float4*)(aptr + (s + 3) * 32 + 8);
                        po3 = *(const float4*)(aptr + (s + 3) * 32 + 12);
                    }
                    if (s + 2 < NSTEP_) {
                        *(bf16x8*)&As[0][woffA0] = cvt8(pe0, pe1);
                        *(bf16x8*)&As[0][woffA1] = cvt8(pe2, pe3);
                    }
                }
                {
                    bf16x8 a0 = (MODE & 1) ? *(const bf16x8*)&As[1][roff0] : ac;
                    bf16x8 a1 = (MODE & 1) ? *(const bf16x8*)&As[1][roff1] : ac;
#pragma unroll
                    for (int cf = 0; cf < 8; ++cf) {
                        bf16x8 bv = (MODE & 2) ? *(const bf16x8*)&Bs[1][cf * 512 + lane * 8] : ac;
                        acc[cf][0] = __builtin_amdgcn_mfma_f32_16x16x32_bf16(a0, bv, acc[cf][0], 0, 0, 0);
                        acc[cf][1] = __builtin_amdgcn_mfma_f32_16x16x32_bf16(a1, bv, acc[cf][1], 0, 0, 0);
                    }
                }
                __syncthreads();
            }
        }
    }

    float sum = 0.f;
#pragma unroll
    for (int cf = 0; cf < 8; ++cf)
#pragma unroll
        for (int q = 0; q < 2; ++q)
#pragma unroll
            for (int i = 0; i < 4; ++i) sum += acc[cf][q][i];
    outp[(size_t)bx * 256 + tid] = sum;
}

// ---------------------------------------------------------------------------
// agg (r11, unchanged, passing)
// ---------------------------------------------------------------------------
__global__ __launch_bounds__(256) void agg_kernel(
    const float* __restrict__ tokens, const int* __restrict__ active,
    const int* __restrict__ cmap, const float* __restrict__ gate_part,
    const float* __restrict__ b2,
    float* __restrict__ out_tok, float* __restrict__ out_act)
{
    __shared__ float wls[NB_];
    __shared__ float red[256];
    __shared__ int   idxs[NB_];
    __shared__ float wts[NB_];
    __shared__ int   gbase[17];

    const int b = blockIdx.x >> 6, c = blockIdx.x & 63;
    const int tid = threadIdx.x, lane = tid & 63, wid = tid >> 6;
    const float b2v = b2[0];
    const float* g0 = gate_part + b * NB_;
    const float* g1 = gate_part + (size_t)B_ * NB_ + b * NB_;
    const float* g2 = gate_part + (size_t)2 * B_ * NB_ + b * NB_;

    float lmax = -INFINITY;
    for (int n = tid; n < NB_; n += 256) {
        const bool msk = (active[b * NB_ + n] != 0) && (cmap[n] == c);
        const float g  = msk ? (g0[n] + g1[n] + g2[n] + b2v) : -INFINITY;
        wls[n] = g;
        lmax = fmaxf(lmax, g);
    }
    red[tid] = lmax; __syncthreads();
    for (int s = 128; s > 0; s >>= 1) {
        if (tid < s) red[tid] = fmaxf(red[tid], red[tid + s]);
        __syncthreads();
    }
    const float m = red[0]; __syncthreads();
    const float msafe = (m > -INFINITY) ? m : 0.f;

    float lsum = 0.f;
    for (int n = tid; n < NB_; n += 256) {
        const float g = wls[n];
        const float e = (g > -INFINITY) ? __expf(g - msafe) : 0.f;
        wls[n] = e; lsum += e;
    }
    red[tid] = lsum; __syncthreads();
    for (int s = 128; s > 0; s >>= 1) {
        if (tid < s) red[tid] += red[tid + s];
        __syncthreads();
    }
    const float ssum = red[0];
    const float inv  = (ssum > 0.f) ? 1.f / ssum : 0.f;
    __syncthreads();

#pragma unroll
    for (int it = 0; it < 4; ++it) {
        const int n = it * 256 + wid * 64 + lane;
        const unsigned long long mask = __ballot(wls[n] > 0.f);
        if (lane == 0) gbase[1 + it * 4 + wid] = __popcll(mask);
    }
    __syncthreads();
    if (tid == 0) {
        gbase[0] = 0;
        for (int i = 1; i <= 16; ++i) gbase[i] += gbase[i - 1];
    }
    __syncthreads();
#pragma unroll
    for (int it = 0; it < 4; ++it) {
        const int n = it * 256 + wid * 64 + lane;
        const float e = wls[n];
        const unsigned long long mask = __ballot(e > 0.f);
        if (e > 0.f) {
            const int pos = gbase[it * 4 + wid] +
                            __popcll(mask & ((1ull << lane) - 1ull));
            idxs[pos] = n;
            wts[pos]  = e * inv;
        }
    }
    __syncthreads();
    const int cnt = gbase[16];

    if (tid < 192) {
        const int d = tid * 4;
        const float* tb = tokens + (size_t)b * NB_ * H_ + d;
        float4 a = {0.f, 0.f, 0.f, 0.f};
        for (int i = 0; i < cnt; ++i) {
            const float wv = wts[i];
            const float4 v = *(const float4*)(tb + (size_t)idxs[i] * H_);
            a.x += wv * v.x; a.y += wv * v.y;
            a.z += wv * v.z; a.w += wv * v.w;
        }
        *(float4*)(out_tok + ((size_t)(b * C_ + c)) * H_ + d) = a;
    }
    if (tid == 0) out_act[b * C_ + c] = (m > -INFINITY) ? 1.f : 0.f;
}

// ---------------------------------------------------------------------------
extern "C" void kernel_launch(void* const* d_in, const int* in_sizes, int n_in,
                              void* d_out, int out_size, void* d_ws, size_t ws_size,
                              hipStream_t stream)
{
    const float* tokens = (const float*)d_in[0];
    const int*   active = (const int*)  d_in[1];
    const int*   cmap   = (const int*)  d_in[2];
    const float* W1     = (const float*)d_in[3];
    const float* b1     = (const float*)d_in[4];
    const float* W2     = (const float*)d_in[5];
    const float* b2     = (const float*)d_in[6];

    float* out      = (float*)d_out;
    float* out_act  = out + (size_t)B_ * C_ * H_;

    short* swz     = (short*)d_ws;                          // 589824 B
    float* gatep   = (float*)((char*)d_ws + 589824);        // 393216 B
    int*   list    = (int*)  ((char*)d_ws + 983040);        // 131072 B
    int*   cntb    = (int*)  ((char*)d_ws + 1114112);       // 128 B
    float* probeo  = (float*)((char*)d_ws + (4u << 20));    // 786 KB probe scratch

    compact_kernel<<<B_, 1024, 0, stream>>>(active, list, cntb);
    prep_w1<<<(H_ * K_) / 256, 256, 0, stream>>>(W1, swz);
    gate_kernel<<<B_ * 24, 256, 0, stream>>>(tokens, swz, b1, W2, list, cntb, gatep);
    agg_kernel<<<B_ * C_, 256, 0, stream>>>(tokens, active, cmap, gatep, b2, out, out_act);

    // ---- diagnostic probes (write only to ws scratch; results unread)
    if (ws_size >= (8u << 20)) {
        probe_kernel<3, 6><<<B_ * 24, 256, 0, stream>>>(tokens, swz, list, cntb, probeo);   // full x6
        probe_kernel<1, 5><<<B_ * 24, 256, 0, stream>>>(tokens, swz, list, cntb, probeo);   // A-only x5
        probe_kernel<2, 5><<<B_ * 24, 256, 0, stream>>>(tokens, swz, list, cntb, probeo);   // B-only x5
        probe_kernel<0, 64><<<B_ * 24, 256, 0, stream>>>(tokens, swz, list, cntb, probeo);  // MFMA x64
    }
}

// Round 13
// 57.411 us; speedup vs baseline: 12.9805x; 12.9805x over previous
//
#include <hip/hip_runtime.h>
#include <math.h>

#define B_    32
#define NB_   1024
#define H_    768
#define K_    384
#define C_    64
#define MC_   128                // rows per gate block
#define NSTEP_ 24                // K-steps of 32

typedef __attribute__((ext_vector_type(8))) short bf16x8;
typedef __attribute__((ext_vector_type(4))) float f32x4;

__device__ __forceinline__ short f2bf(float f) {   // RNE fp32 -> bf16 bits
    unsigned u = __float_as_uint(f);
    unsigned r = (u + 0x7fffu + ((u >> 16) & 1u)) >> 16;
    return (short)r;
}
__device__ __forceinline__ bf16x8 cvt8(const float4& a, const float4& b) {
    bf16x8 v = { f2bf(a.x), f2bf(a.y), f2bf(a.z), f2bf(a.w),
                 f2bf(b.x), f2bf(b.y), f2bf(b.z), f2bf(b.w) };
    return v;
}
__device__ __forceinline__ float ftanh(float x) {  // tanh = 1 - 2/(e^2x+1)
    float e = __expf(2.f * x);
    return 1.f - 2.f * __builtin_amdgcn_rcpf(e + 1.f);
}
__device__ __forceinline__ void gload_lds16(const void* g, void* l) {
    __builtin_amdgcn_global_load_lds(
        (const __attribute__((address_space(1))) unsigned int*)g,
        (__attribute__((address_space(3))) unsigned int*)l, 16, 0, 0);
}

// ---------------------------------------------------------------------------
// W1 -> bf16, fragment-ordered per (nt, step): 8KB contiguous slabs.
// ---------------------------------------------------------------------------
__global__ __launch_bounds__(256) void prep_w1(const float* __restrict__ W1,
                                               short* __restrict__ swz)
{
    int idx = blockIdx.x * 256 + threadIdx.x;
    int k = idx / K_, n = idx % K_;
    float v = W1[idx];
    int step = k >> 5, lg = (k >> 3) & 3, i = k & 7;
    int nt = n >> 7, cf = (n >> 4) & 7, nn = n & 15;
    swz[(((nt * 24 + step) * 8) + cf) * 512 + (lg * 16 + nn) * 8 + i] = f2bf(v);
}

// ---------------------------------------------------------------------------
__global__ __launch_bounds__(1024) void compact_kernel(
    const int* __restrict__ active, int* __restrict__ list, int* __restrict__ cnt)
{
    __shared__ int wsum[16];
    __shared__ int wbase[17];
    const int b = blockIdx.x, tid = threadIdx.x, lane = tid & 63, wid = tid >> 6;
    const int flag = active[b * NB_ + tid] != 0;
    const unsigned long long m = __ballot(flag);
    if (lane == 0) wsum[wid] = __popcll(m);
    __syncthreads();
    if (tid == 0) {
        int r = 0;
        for (int i = 0; i < 16; ++i) { wbase[i] = r; r += wsum[i]; }
        wbase[16] = r;
        cnt[b] = r;
    }
    __syncthreads();
    const int total = wbase[16];
    if (flag) {
        const int pos = wbase[wid] + __popcll(m & ((1ull << lane) - 1ull));
        list[b * NB_ + pos] = tid;
    }
    if (tid >= total) list[b * NB_ + tid] = 0;
}

// ---------------------------------------------------------------------------
// Gate MLP, m97-style 128x128xK768 tiles + T4 counted-vmcnt barriers.
// Grid 576: bid = ((grp*3+nt)*8)|xcd so nt-triples of one (b,chunk) share an
// XCD (duplicated A-reads become L2 hits). Per K-step: B slab via
// global_load_lds dwordx4 (dbuf), A reg-staged (4 float4, 2 steps ahead) ->
// bf16 LDS (dbuf), 16 MFMA/wave, then s_waitcnt vmcnt(4) lgkmcnt(0) +
// raw s_barrier: the 4 A-loads stay in flight ACROSS the barrier.
// Last iteration peeled with vmcnt(0) (no A-loads outstanding there).
// ---------------------------------------------------------------------------
__global__ __launch_bounds__(256, 3) void gate_kernel(
    const float* __restrict__ tokens, const short* __restrict__ swz,
    const float* __restrict__ b1, const float* __restrict__ W2,
    const int* __restrict__ list, const int* __restrict__ cnt,
    float* __restrict__ gate_part)
{
    __shared__ __align__(16) short As[2][4096];
    __shared__ __align__(16) short Bs[2][4096];

    const int bx   = blockIdx.x;
    const int xcd  = bx & 7;
    const int q    = bx >> 3;          // 0..71
    const int grp  = q / 3;            // 0..23
    const int nt   = q % 3;
    const int p    = grp * 8 + xcd;    // 0..191
    const int b    = p / 6;            // 0..31
    const int chunk = p % 6;           // 0..5  (768-row coverage)
    if (chunk * MC_ >= cnt[b]) return;

    const int tid  = threadIdx.x;
    const int lane = tid & 63;
    const int w    = tid >> 6;
    const int lrow = lane & 15;
    const int kg   = lane >> 4;

    const int r = tid >> 1, h = tid & 1;
    const int nrow = list[b * NB_ + chunk * MC_ + r];
    const float* aptr = tokens + ((size_t)b * NB_ + nrow) * H_ + h * 16;
    const int rg = r >> 4, arow = r & 15;
    const int woffA0 = ((rg * 4 + 2 * h)     * 16 + (arow ^ (4 * h)))     * 8;
    const int woffA1 = ((rg * 4 + 2 * h + 1) * 16 + (arow ^ (4 * h + 2))) * 8;

    const char* bsrc = (const char*)swz + (size_t)nt * 196608 + w * 1024 + lane * 16;
    char* bdst0 = (char*)&Bs[0][0] + w * 1024;
    char* bdst1 = (char*)&Bs[1][0] + w * 1024;

    const int roff0 = (((2 * w + 0) * 4 + kg) * 16 + (lrow ^ (kg << 1))) * 8;
    const int roff1 = (((2 * w + 1) * 4 + kg) * 16 + (lrow ^ (kg << 1))) * 8;

    f32x4 acc[8][2];
#pragma unroll
    for (int cf = 0; cf < 8; ++cf)
#pragma unroll
        for (int qq = 0; qq < 2; ++qq) acc[cf][qq] = (f32x4){0.f, 0.f, 0.f, 0.f};

    float4 pe0, pe1, pe2, pe3, po0, po1, po2, po3;

    // ---- prologue: B[0] (gload_lds, issued first), A[0]->pe, A[1]->po,
    //      cvt pe -> As[0].  Barrier keeps po (4 newest) in flight.
    gload_lds16(bsrc,        bdst0);
    gload_lds16(bsrc + 4096, bdst0 + 4096);
    __builtin_amdgcn_sched_barrier(0);
    pe0 = *(const float4*)(aptr);
    pe1 = *(const float4*)(aptr + 4);
    pe2 = *(const float4*)(aptr + 8);
    pe3 = *(const float4*)(aptr + 12);
    po0 = *(const float4*)(aptr + 32);
    po1 = *(const float4*)(aptr + 36);
    po2 = *(const float4*)(aptr + 40);
    po3 = *(const float4*)(aptr + 44);
    *(bf16x8*)&As[0][woffA0] = cvt8(pe0, pe1);   // compiler waits pe (drains B0 too)
    *(bf16x8*)&As[0][woffA1] = cvt8(pe2, pe3);
    asm volatile("s_waitcnt vmcnt(4) lgkmcnt(0)" ::: "memory");
    __builtin_amdgcn_s_barrier();
    __builtin_amdgcn_sched_barrier(0);

    // ---- steady loop: s = 0..20 (all prefetch guards statically true)
    for (int s = 0; s <= 20; s += 2) {
        // ===== even half: compute step s from As[0]/Bs[0]
        {
            const char* bp = bsrc + (size_t)(s + 1) * 8192;   // B[s+1] -> Bs[1]
            gload_lds16(bp,        bdst1);
            gload_lds16(bp + 4096, bdst1 + 4096);
        }
        __builtin_amdgcn_sched_barrier(0);                    // pin B before A
        pe0 = *(const float4*)(aptr + (s + 2) * 32);          // A[s+2]
        pe1 = *(const float4*)(aptr + (s + 2) * 32 + 4);
        pe2 = *(const float4*)(aptr + (s + 2) * 32 + 8);
        pe3 = *(const float4*)(aptr + (s + 2) * 32 + 12);
        *(bf16x8*)&As[1][woffA0] = cvt8(po0, po1);            // A[s+1] -> As[1]
        *(bf16x8*)&As[1][woffA1] = cvt8(po2, po3);
        {
            bf16x8 a0 = *(const bf16x8*)&As[0][roff0];
            bf16x8 a1 = *(const bf16x8*)&As[0][roff1];
#pragma unroll
            for (int cf = 0; cf < 8; ++cf) {
                bf16x8 bv = *(const bf16x8*)&Bs[0][cf * 512 + lane * 8];
                acc[cf][0] = __builtin_amdgcn_mfma_f32_16x16x32_bf16(a0, bv, acc[cf][0], 0, 0, 0);
                acc[cf][1] = __builtin_amdgcn_mfma_f32_16x16x32_bf16(a1, bv, acc[cf][1], 0, 0, 0);
            }
        }
        asm volatile("s_waitcnt vmcnt(4) lgkmcnt(0)" ::: "memory");
        __builtin_amdgcn_s_barrier();
        __builtin_amdgcn_sched_barrier(0);

        // ===== odd half: compute step s+1 from As[1]/Bs[1]
        {
            const char* bp = bsrc + (size_t)(s + 2) * 8192;   // B[s+2] -> Bs[0]
            gload_lds16(bp,        bdst0);
            gload_lds16(bp + 4096, bdst0 + 4096);
        }
        __builtin_amdgcn_sched_barrier(0);
        po0 = *(const float4*)(aptr + (s + 3) * 32);          // A[s+3]
        po1 = *(const float4*)(aptr + (s + 3) * 32 + 4);
        po2 = *(const float4*)(aptr + (s + 3) * 32 + 8);
        po3 = *(const float4*)(aptr + (s + 3) * 32 + 12);
        *(bf16x8*)&As[0][woffA0] = cvt8(pe0, pe1);            // A[s+2] -> As[0]
        *(bf16x8*)&As[0][woffA1] = cvt8(pe2, pe3);
        {
            bf16x8 a0 = *(const bf16x8*)&As[1][roff0];
            bf16x8 a1 = *(const bf16x8*)&As[1][roff1];
#pragma unroll
            for (int cf = 0; cf < 8; ++cf) {
                bf16x8 bv = *(const bf16x8*)&Bs[1][cf * 512 + lane * 8];
                acc[cf][0] = __builtin_amdgcn_mfma_f32_16x16x32_bf16(a0, bv, acc[cf][0], 0, 0, 0);
                acc[cf][1] = __builtin_amdgcn_mfma_f32_16x16x32_bf16(a1, bv, acc[cf][1], 0, 0, 0);
            }
        }
        asm volatile("s_waitcnt vmcnt(4) lgkmcnt(0)" ::: "memory");
        __builtin_amdgcn_s_barrier();
        __builtin_amdgcn_sched_barrier(0);
    }

    // ---- peeled tail: steps 22 and 23 (no A prefetch outstanding -> vmcnt(0))
    {
        const char* bp = bsrc + (size_t)23 * 8192;            // B[23] -> Bs[1]
        gload_lds16(bp,        bdst1);
        gload_lds16(bp + 4096, bdst1 + 4096);
    }
    __builtin_amdgcn_sched_barrier(0);
    *(bf16x8*)&As[1][woffA0] = cvt8(po0, po1);                // A[23] -> As[1]
    *(bf16x8*)&As[1][woffA1] = cvt8(po2, po3);
    {
        bf16x8 a0 = *(const bf16x8*)&As[0][roff0];            // step 22
        bf16x8 a1 = *(const bf16x8*)&As[0][roff1];
#pragma unroll
        for (int cf = 0; cf < 8; ++cf) {
            bf16x8 bv = *(const bf16x8*)&Bs[0][cf * 512 + lane * 8];
            acc[cf][0] = __builtin_amdgcn_mfma_f32_16x16x32_bf16(a0, bv, acc[cf][0], 0, 0, 0);
            acc[cf][1] = __builtin_amdgcn_mfma_f32_16x16x32_bf16(a1, bv, acc[cf][1], 0, 0, 0);
        }
    }
    asm volatile("s_waitcnt vmcnt(0) lgkmcnt(0)" ::: "memory");
    __builtin_amdgcn_s_barrier();
    __builtin_amdgcn_sched_barrier(0);
    {
        bf16x8 a0 = *(const bf16x8*)&As[1][roff0];            // step 23
        bf16x8 a1 = *(const bf16x8*)&As[1][roff1];
#pragma unroll
        for (int cf = 0; cf < 8; ++cf) {
            bf16x8 bv = *(const bf16x8*)&Bs[1][cf * 512 + lane * 8];
            acc[cf][0] = __builtin_amdgcn_mfma_f32_16x16x32_bf16(a0, bv, acc[cf][0], 0, 0, 0);
            acc[cf][1] = __builtin_amdgcn_mfma_f32_16x16x32_bf16(a1, bv, acc[cf][1], 0, 0, 0);
        }
    }

    // ---- epilogue: partial gate = sum_{n in tile} tanh(h + b1[n]) * W2[n]
    float ps[2][4];
#pragma unroll
    for (int qq = 0; qq < 2; ++qq)
#pragma unroll
        for (int i = 0; i < 4; ++i) ps[qq][i] = 0.f;

#pragma unroll
    for (int cf = 0; cf < 8; ++cf) {
        const int n = nt * 128 + cf * 16 + lrow;
        const float bb = b1[n];
        const float ww = W2[n];
#pragma unroll
        for (int qq = 0; qq < 2; ++qq)
#pragma unroll
            for (int i = 0; i < 4; ++i)
                ps[qq][i] += ftanh(acc[cf][qq][i] + bb) * ww;
    }
#pragma unroll
    for (int m = 1; m < 16; m <<= 1)
#pragma unroll
        for (int qq = 0; qq < 2; ++qq)
#pragma unroll
            for (int i = 0; i < 4; ++i)
                ps[qq][i] += __shfl_xor(ps[qq][i], m, 64);

    if (lrow == 0) {
        float* gp = gate_part + (size_t)nt * (B_ * NB_) + b * NB_;
#pragma unroll
        for (int qq = 0; qq < 2; ++qq)
#pragma unroll
            for (int i = 0; i < 4; ++i) {
                const int rl = w * 32 + qq * 16 + kg * 4 + i;
                gp[list[b * NB_ + chunk * MC_ + rl]] = ps[qq][i];
            }
    }
}

// ---------------------------------------------------------------------------
// Per-(b,c) masked softmax + weighted token sum; gate = sum of 3 partials + b2.
// ---------------------------------------------------------------------------
__global__ __launch_bounds__(256) void agg_kernel(
    const float* __restrict__ tokens, const int* __restrict__ active,
    const int* __restrict__ cmap, const float* __restrict__ gate_part,
    const float* __restrict__ b2,
    float* __restrict__ out_tok, float* __restrict__ out_act)
{
    __shared__ float wls[NB_];
    __shared__ float red[256];
    __shared__ int   idxs[NB_];
    __shared__ float wts[NB_];
    __shared__ int   gbase[17];

    const int b = blockIdx.x >> 6, c = blockIdx.x & 63;
    const int tid = threadIdx.x, lane = tid & 63, wid = tid >> 6;
    const float b2v = b2[0];
    const float* g0 = gate_part + b * NB_;
    const float* g1 = gate_part + (size_t)B_ * NB_ + b * NB_;
    const float* g2 = gate_part + (size_t)2 * B_ * NB_ + b * NB_;

    float lmax = -INFINITY;
    for (int n = tid; n < NB_; n += 256) {
        const bool msk = (active[b * NB_ + n] != 0) && (cmap[n] == c);
        const float g  = msk ? (g0[n] + g1[n] + g2[n] + b2v) : -INFINITY;
        wls[n] = g;
        lmax = fmaxf(lmax, g);
    }
    red[tid] = lmax; __syncthreads();
    for (int s = 128; s > 0; s >>= 1) {
        if (tid < s) red[tid] = fmaxf(red[tid], red[tid + s]);
        __syncthreads();
    }
    const float m = red[0]; __syncthreads();
    const float msafe = (m > -INFINITY) ? m : 0.f;

    float lsum = 0.f;
    for (int n = tid; n < NB_; n += 256) {
        const float g = wls[n];
        const float e = (g > -INFINITY) ? __expf(g - msafe) : 0.f;
        wls[n] = e; lsum += e;
    }
    red[tid] = lsum; __syncthreads();
    for (int s = 128; s > 0; s >>= 1) {
        if (tid < s) red[tid] += red[tid + s];
        __syncthreads();
    }
    const float ssum = red[0];
    const float inv  = (ssum > 0.f) ? 1.f / ssum : 0.f;
    __syncthreads();

#pragma unroll
    for (int it = 0; it < 4; ++it) {
        const int n = it * 256 + wid * 64 + lane;
        const unsigned long long mask = __ballot(wls[n] > 0.f);
        if (lane == 0) gbase[1 + it * 4 + wid] = __popcll(mask);
    }
    __syncthreads();
    if (tid == 0) {
        gbase[0] = 0;
        for (int i = 1; i <= 16; ++i) gbase[i] += gbase[i - 1];
    }
    __syncthreads();
#pragma unroll
    for (int it = 0; it < 4; ++it) {
        const int n = it * 256 + wid * 64 + lane;
        const float e = wls[n];
        const unsigned long long mask = __ballot(e > 0.f);
        if (e > 0.f) {
            const int pos = gbase[it * 4 + wid] +
                            __popcll(mask & ((1ull << lane) - 1ull));
            idxs[pos] = n;
            wts[pos]  = e * inv;
        }
    }
    __syncthreads();
    const int cnt = gbase[16];

    if (tid < 192) {
        const int d = tid * 4;
        const float* tb = tokens + (size_t)b * NB_ * H_ + d;
        float4 a = {0.f, 0.f, 0.f, 0.f};
        for (int i = 0; i < cnt; ++i) {
            const float wv = wts[i];
            const float4 v = *(const float4*)(tb + (size_t)idxs[i] * H_);
            a.x += wv * v.x; a.y += wv * v.y;
            a.z += wv * v.z; a.w += wv * v.w;
        }
        *(float4*)(out_tok + ((size_t)(b * C_ + c)) * H_ + d) = a;
    }
    if (tid == 0) out_act[b * C_ + c] = (m > -INFINITY) ? 1.f : 0.f;
}

// ---------------------------------------------------------------------------
extern "C" void kernel_launch(void* const* d_in, const int* in_sizes, int n_in,
                              void* d_out, int out_size, void* d_ws, size_t ws_size,
                              hipStream_t stream)
{
    const float* tokens = (const float*)d_in[0];
    const int*   active = (const int*)  d_in[1];
    const int*   cmap   = (const int*)  d_in[2];
    const float* W1     = (const float*)d_in[3];
    const float* b1     = (const float*)d_in[4];
    const float* W2     = (const float*)d_in[5];
    const float* b2     = (const float*)d_in[6];

    float* out      = (float*)d_out;
    float* out_act  = out + (size_t)B_ * C_ * H_;

    short* swz     = (short*)d_ws;                          // 589824 B
    float* gatep   = (float*)((char*)d_ws + 589824);        // 393216 B (3 planes)
    int*   list    = (int*)  ((char*)d_ws + 983040);        // 131072 B
    int*   cntb    = (int*)  ((char*)d_ws + 1114112);       // 128 B

    compact_kernel<<<B_, 1024, 0, stream>>>(active, list, cntb);
    prep_w1<<<(H_ * K_) / 256, 256, 0, stream>>>(W1, swz);
    gate_kernel<<<576, 256, 0, stream>>>(tokens, swz, b1, W2, list, cntb, gatep);
    agg_kernel<<<B_ * C_, 256, 0, stream>>>(tokens, active, cmap, gatep, b2, out, out_act);
}